// Round 3
// baseline (343.198 us; speedup 1.0000x reference)
//
#include <hip/hip_runtime.h>
#include <math.h>

#define N_ 32
#define D_ 512
#define S_ 1600
#define K_ 64
#define NSP 16   // agg partials per n (blocks per n)

#define AP 72    // a' pitch (bf16 elems): 144 B rows, 16B-aligned b128 frags

typedef __attribute__((ext_vector_type(8))) short short8;   // 8 bf16 (A/B frag)
typedef __attribute__((ext_vector_type(4))) float f32x4;    // acc frag
typedef __attribute__((ext_vector_type(2))) unsigned u32x2; // 8-B LDS store

// float -> bf16 (round to nearest even), bit pattern in short
static __device__ __forceinline__ short f2bf(float f) {
    unsigned u = __float_as_uint(f);
    u += 0x7fffu + ((u >> 16) & 1u);
    return (short)(u >> 16);
}
// pack two floats into (bf16(a) | bf16(b)<<16)
static __device__ __forceinline__ unsigned pk2(float a, float b) {
    return (unsigned)(unsigned short)f2bf(a) | ((unsigned)(unsigned short)f2bf(b) << 16);
}

// ---------------------------------------------------------------------------
// kW: conv_weight [64][512] fp32 -> bf16
// ---------------------------------------------------------------------------
__global__ __launch_bounds__(256) void kW(const float* __restrict__ w,
                                          short* __restrict__ w16)
{
    int i4 = (blockIdx.x * 256 + threadIdx.x) * 4;   // 32 blocks: 32768 elems
    float4 v = *(const float4*)&w[i4];
    short4 h = {f2bf(v.x), f2bf(v.y), f2bf(v.z), f2bf(v.w)};
    *(short4*)&w16[i4] = h;
}

// ---------------------------------------------------------------------------
// kF: fused logits -> softmax -> agg. One block per (n, bj); bj in [0,16).
// Tiles {bj} and {bj+16 if bj<9} (64 s each). 256 thr / 4 waves.
// Registers: acc[4][8] = 128 AGPR + ~100 arch < 256 cap (launch_bounds 256,2)
// -> no spill, 2 blocks/CU (LDS 74.5 KB), grid 512 = all resident, two
// independent barrier domains per CU. 4 barriers per tile.
// T layout: [s][d] pitch 512 bf16, XOR-swizzle elem ^= (s&7)<<3 (conflict-
// even b128 reads). No-max softmax (|logits| <= ~1.2). ssq via LDS atomics.
// Wave wv: logits k in [16wv,16wv+16) x all 64 s; agg 128 d at wv*128.
// MFMA conv: D[row=4q+r][col=lane&15]; row<-1st operand, col<-2nd.
// ---------------------------------------------------------------------------
__global__ __launch_bounds__(256, 2) void kF(const float* __restrict__ x,
                                             const short* __restrict__ w16,
                                             float* __restrict__ aggp,
                                             float* __restrict__ asum)
{
    __shared__ short T[64 * 512];       // x-tile, [s][d] XOR-swizzled (64 KB)
    __shared__ short aP[64 * AP];       // a' = softmax*inv, [k][s] (9.2 KB)
    __shared__ float invSS[64];         // atomic ssq accumulator
    __shared__ float invL[64];
    __shared__ float wredS[4][66];      // cross-wave softmax sums (1 KB)

    const int tid = threadIdx.x;
    const int wv  = tid >> 6;           // wave 0..3
    const int l   = tid & 63;
    const int lk  = l & 15;
    const int q   = l >> 4;
    const int n   = blockIdx.x >> 4;
    const int bj  = blockIdx.x & 15;
    const int nst = (bj < 9) ? 2 : 1;

    const float* xb = x + (size_t)n * D_ * S_;

    f32x4 acc[4][8];                    // agg acc: [kt][ds] (128 AGPR)
#pragma unroll
    for (int a = 0; a < 4; ++a)
#pragma unroll
        for (int b = 0; b < 8; ++b) acc[a][b] = (f32x4){0.f, 0.f, 0.f, 0.f};
    float asum_loc[4] = {0.f, 0.f, 0.f, 0.f};

    // staging: lane holds s = 4lk+q after transpose; XOR mask (s&7)<<3 elems
    const int sT     = 4 * lk + q;
    const int sTbase = sT * 512;
    const int smask  = (sT & 7) << 3;
    const int rmask  = (lk & 7) << 3;   // logits read rows st*16+lk: &7 == lk&7

    if (tid < 64) invSS[tid] = 0.f;
    __syncthreads();

    for (int it = 0; it < nst; ++it) {
        const int s0 = (bj + 16 * it) * 64;

        // ---- stage x-tile: fp32 -> bf16, 4x4 in-register lane transpose ----
        // lane loads float4 = x[d = 16j + 4wv + q][s0 + 4lk .. +3]
        float ssql[4] = {0.f, 0.f, 0.f, 0.f};
#pragma unroll
        for (int j = 0; j < 32; ++j) {
            const int d = 16 * j + 4 * wv + q;
            const float4 v = *(const float4*)&xb[(size_t)d * S_ + s0 + 4 * lk];
            ssql[0] += v.x * v.x;  ssql[1] += v.y * v.y;
            ssql[2] += v.z * v.z;  ssql[3] += v.w * v.w;
            unsigned p0 = pk2(v.x, v.y), p1 = pk2(v.z, v.w);
            // stage 1: exchange halves across lane bit 5
            unsigned mine = (l & 32) ? p0 : p1;
            unsigned oth  = (unsigned)__shfl_xor((int)mine, 32);
            unsigned a0 = (l & 32) ? oth : p0;
            unsigned a1 = (l & 32) ? p1 : oth;
            // stage 2: u16 interleave across lane bit 4
            unsigned r0 = (unsigned)__shfl_xor((int)a0, 16);
            unsigned r1 = (unsigned)__shfl_xor((int)a1, 16);
            unsigned o0, o1;
            if (l & 16) {
                o0 = (r0 >> 16) | (a0 & 0xffff0000u);
                o1 = (r1 >> 16) | (a1 & 0xffff0000u);
            } else {
                o0 = (a0 & 0xffffu) | (r0 << 16);
                o1 = (a1 & 0xffffu) | (r1 << 16);
            }
            // lane holds s = 4lk+q, d-run [16j+4wv, +3] -> one b64 store
            *(u32x2*)&T[sTbase + ((16 * j + 4 * wv) ^ smask)] = (u32x2){o0, o1};
        }
#pragma unroll
        for (int i = 0; i < 4; ++i) atomicAdd(&invSS[4 * lk + i], ssql[i]);
        __syncthreads();   // (A) T + invSS ready

        if (tid < 64) {
            invL[tid] = 1.0f / fmaxf(sqrtf(invSS[tid]), 1e-12f);
            invSS[tid] = 0.f;           // re-zero for next tile (next adds after D)
        }

        // ---- logits GEMM: wave: [16 k] x [64 s], K-dim d=512 ----
        f32x4 accl[4];
#pragma unroll
        for (int st = 0; st < 4; ++st) accl[st] = (f32x4){0.f, 0.f, 0.f, 0.f};
        const short* wrow = w16 + (size_t)(16 * wv + lk) * D_;
#pragma unroll
        for (int kst = 0; kst < 16; ++kst) {
            short8 af = *(const short8*)&wrow[kst * 32 + q * 8];
            const int off = (kst * 32 + q * 8) ^ rmask;
#pragma unroll
            for (int st = 0; st < 4; ++st) {
                short8 b = *(const short8*)&T[(st * 16 + lk) * 512 + off];
                accl[st] = __builtin_amdgcn_mfma_f32_16x16x32_bf16(af, b, accl[st], 0, 0, 0);
            }
        }
        __syncthreads();   // (B) invL ready; all T reads done

        // ---- softmax over k (no max subtraction; |logit| <= ~1.2) ----
        float e[4][4], invv[4];
#pragma unroll
        for (int st = 0; st < 4; ++st) {
            invv[st] = invL[st * 16 + lk];
            float sm = 0.f;
#pragma unroll
            for (int r = 0; r < 4; ++r) {
                e[st][r] = __expf(accl[st][r] * invv[st]);
                sm += e[st][r];
            }
            sm += __shfl_xor(sm, 16);
            sm += __shfl_xor(sm, 32);
            if (q == 0) wredS[wv][st * 16 + lk] = sm;
        }
        __syncthreads();   // (C) wredS ready
#pragma unroll
        for (int st = 0; st < 4; ++st) {
            const int s = st * 16 + lk;
            const float rs = 1.0f / (wredS[0][s] + wredS[1][s]
                                   + wredS[2][s] + wredS[3][s]);
#pragma unroll
            for (int r = 0; r < 4; ++r) {
                const float p = e[st][r] * rs;
                aP[(16 * wv + 4 * q + r) * AP + s] = f2bf(p * invv[st]);
                asum_loc[r] += p;
            }
        }
        __syncthreads();   // (D) aP ready

        // ---- agg GEMM: acc[k][d] += a'[k][s] * x[d][s], K-dim s=64 ----
        // x B-frags re-read from global (L2 hit: staged moments ago)
        const int dbase = wv * 128;
#pragma unroll
        for (int k2 = 0; k2 < 2; ++k2) {
            const int sA = k2 * 32 + q * 8;
            short8 afr[4];
#pragma unroll
            for (int kt = 0; kt < 4; ++kt)
                afr[kt] = *(const short8*)&aP[(kt * 16 + lk) * AP + sA];
#pragma unroll
            for (int dsh = 0; dsh < 2; ++dsh) {
                short8 bfr[4];
#pragma unroll
                for (int dv = 0; dv < 4; ++dv) {
                    const int d = dbase + (dsh * 4 + dv) * 16 + lk;
                    const float* xp = &xb[(size_t)d * S_ + s0 + sA];
                    float4 v0 = *(const float4*)xp;
                    float4 v1 = *(const float4*)(xp + 4);
                    short8 b;
                    b[0] = f2bf(v0.x); b[1] = f2bf(v0.y); b[2] = f2bf(v0.z); b[3] = f2bf(v0.w);
                    b[4] = f2bf(v1.x); b[5] = f2bf(v1.y); b[6] = f2bf(v1.z); b[7] = f2bf(v1.w);
                    bfr[dv] = b;
                }
#pragma unroll
                for (int kt = 0; kt < 4; ++kt)
#pragma unroll
                    for (int dv = 0; dv < 4; ++dv)
                        acc[kt][dsh * 4 + dv] = __builtin_amdgcn_mfma_f32_16x16x32_bf16(
                            afr[kt], bfr[dv], acc[kt][dsh * 4 + dv], 0, 0, 0);
            }
        }
        // loop back: next staging writes T only; T reads all completed before
        // (B); aP reads complete before next (D). No barrier needed here.
    }

    // ---- write agg partial: aggp[bj][n][k][d] ----
    float* ab = aggp + ((size_t)bj * N_ + n) * K_ * D_;
#pragma unroll
    for (int kt = 0; kt < 4; ++kt)
#pragma unroll
        for (int ds = 0; ds < 8; ++ds)
#pragma unroll
            for (int r = 0; r < 4; ++r)
                ab[(size_t)(kt * 16 + 4 * q + r) * D_ + wv * 128 + ds * 16 + lk] = acc[kt][ds][r];

    // ---- asum: reduce over lk within 16-lane group, one atomic per k ----
#pragma unroll
    for (int r = 0; r < 4; ++r) {
        float v = asum_loc[r];
        v += __shfl_xor(v, 1);  v += __shfl_xor(v, 2);
        v += __shfl_xor(v, 4);  v += __shfl_xor(v, 8);
        if (lk == 0) atomicAdd(&asum[n * K_ + 16 * wv + 4 * q + r], v);
    }
}

// ---------------------------------------------------------------------------
// kC: vlad = (sum of NSP agg partials) - asum*centroid; intra-L2-norm over d;
// global norm = /sqrt(K) = /8 exactly. grid: 2048 blocks x 256 thr.
// ---------------------------------------------------------------------------
__global__ __launch_bounds__(256) void kC(const float* __restrict__ aggp,
                                          const float* __restrict__ asum,
                                          const float* __restrict__ cent,
                                          float* __restrict__ out)
{
    __shared__ float red[4];
    const int tid = threadIdx.x;
    const int nk = blockIdx.x;
    const int k = nk & 63;
    const float as = asum[nk];
    const float* cb = cent + (size_t)k * D_;

    float v0 = 0.f, v1 = 0.f;
#pragma unroll
    for (int p = 0; p < NSP; ++p) {
        const float* ag = aggp + (size_t)p * N_ * K_ * D_ + (size_t)nk * D_;
        v0 += ag[tid];
        v1 += ag[tid + 256];
    }
    v0 -= as * cb[tid];
    v1 -= as * cb[tid + 256];
    float ssq = v0 * v0 + v1 * v1;

    ssq += __shfl_xor(ssq, 32);
    ssq += __shfl_xor(ssq, 16);
    ssq += __shfl_xor(ssq, 8);
    ssq += __shfl_xor(ssq, 4);
    ssq += __shfl_xor(ssq, 2);
    ssq += __shfl_xor(ssq, 1);
    if ((tid & 63) == 0) red[tid >> 6] = ssq;
    __syncthreads();
    const float total = red[0] + red[1] + red[2] + red[3];
    const float scale = 1.0f / (fmaxf(sqrtf(total), 1e-12f) * 8.0f);

    out[(size_t)nk * D_ + tid]       = v0 * scale;
    out[(size_t)nk * D_ + tid + 256] = v1 * scale;
}

// ---------------------------------------------------------------------------
extern "C" void kernel_launch(void* const* d_in, const int* in_sizes, int n_in,
                              void* d_out, int out_size, void* d_ws, size_t ws_size,
                              hipStream_t stream)
{
    const float* x    = (const float*)d_in[0];   // [32,512,40,40]
    const float* w    = (const float*)d_in[1];   // [64,512]
    const float* cent = (const float*)d_in[2];   // [64,512]
    float* out = (float*)d_out;                  // [32, 32768]

    // ws carve (~67.2 MB), 16B-aligned throughout
    float* aggp = (float*)d_ws;                          // NSP*32*64*512 fp32
    float* asum = aggp + (size_t)NSP * N_ * K_ * D_;     // 2048 fp32
    short* w16  = (short*)(asum + N_ * K_);              // 32768 bf16

    hipMemsetAsync(asum, 0, (size_t)N_ * K_ * sizeof(float), stream);

    kW<<<32, 256, 0, stream>>>(w, w16);
    kF<<<N_ * NSP, 256, 0, stream>>>(x, w16, aggp, asum);
    kC<<<N_ * K_, 256, 0, stream>>>(aggp, asum, cent, out);
}

// Round 4
// 232.521 us; speedup vs baseline: 1.4760x; 1.4760x over previous
//
#include <hip/hip_runtime.h>
#include <math.h>

#define N_ 32
#define D_ 512
#define S_ 1600
#define K_ 64

#define APL 72   // aPl relay pitch (bf16): 144 B rows, 16B-aligned b128

typedef __attribute__((ext_vector_type(8))) short short8;   // 8 bf16 (A/B frag)
typedef __attribute__((ext_vector_type(4))) float f32x4;    // acc frag
typedef __attribute__((ext_vector_type(2))) unsigned u32x2; // 8-B LDS store

// float -> bf16 (round to nearest even), bit pattern in short
static __device__ __forceinline__ short f2bf(float f) {
    unsigned u = __float_as_uint(f);
    u += 0x7fffu + ((u >> 16) & 1u);
    return (short)(u >> 16);
}
// pack two floats into (bf16(a) | bf16(b)<<16)
static __device__ __forceinline__ unsigned pk2(float a, float b) {
    return (unsigned)(unsigned short)f2bf(a) | ((unsigned)(unsigned short)f2bf(b) << 16);
}

// ---------------------------------------------------------------------------
// kW: conv_weight [64][512] fp32 -> bf16
// ---------------------------------------------------------------------------
__global__ __launch_bounds__(256) void kW(const float* __restrict__ w,
                                          short* __restrict__ w16)
{
    int i4 = (blockIdx.x * 256 + threadIdx.x) * 4;   // 32 blocks: 32768 elems
    float4 v = *(const float4*)&w[i4];
    short4 h = {f2bf(v.x), f2bf(v.y), f2bf(v.z), f2bf(v.w)};
    *(short4*)&w16[i4] = h;
}

// ---------------------------------------------------------------------------
// kA: logits -> softmax -> aprime (= p*inv, bf16) + asum. One block per
// (n, s-chunk of 64): 800 blocks x 256 thr (4 waves). LDS 74.5 KB -> 2
// blocks/CU; no agg accumulator -> low reg pressure, no spill.
// Staging (from r3, verified): full 512-d tile, in-register 4x4 shfl
// transpose, b64 stores into T[s][d] with XOR swizzle elem ^= (s&7)<<3
// -> conflict-free b128 frag reads. ssq via LDS atomics. No-max softmax
// (|logits| <= ~1.2, verified r2/r3). aprime via LDS relay -> 128 B
// coalesced global rows. 5 barriers per block.
// Wave wv: k in [16wv,16wv+16) x all 64 s.
// MFMA conv: D[row=4q+r][col=lane&15]; row<-1st operand, col<-2nd.
// ---------------------------------------------------------------------------
__global__ __launch_bounds__(256) void kA(const float* __restrict__ x,
                                          const short* __restrict__ w16,
                                          short* __restrict__ aprime,
                                          float* __restrict__ asum)
{
    __shared__ short T[64 * 512];       // x-tile, [s][d] XOR-swizzled (64 KB)
    __shared__ short aPl[64 * APL];     // a' relay [k][s] (9.2 KB)
    __shared__ float invSS[64];         // atomic ssq accumulator
    __shared__ float invL[64];
    __shared__ float wredS[4][66];      // cross-wave softmax sums (1 KB)

    const int tid = threadIdx.x;
    const int wv  = tid >> 6;
    const int l   = tid & 63;
    const int lk  = l & 15;
    const int q   = l >> 4;
    const int n   = blockIdx.x / 25;
    const int s0  = (blockIdx.x % 25) * 64;

    const float* xb = x + (size_t)n * D_ * S_;

    // staging: lane holds s = 4lk+q after transpose; XOR mask (s&7)<<3 elems
    const int sT     = 4 * lk + q;
    const int sTbase = sT * 512;
    const int smask  = (sT & 7) << 3;
    const int rmask  = (lk & 7) << 3;   // read rows st*16+lk: (row&7)==(lk&7)

    if (tid < 64) invSS[tid] = 0.f;
    __syncthreads();

    // ---- stage x-tile: fp32 -> bf16, 4x4 in-register lane transpose ----
    // lane loads float4 = x[d = 16j + 4wv + q][s0 + 4lk .. +3]
    float ssql[4] = {0.f, 0.f, 0.f, 0.f};
#pragma unroll
    for (int j = 0; j < 32; ++j) {
        const int d = 16 * j + 4 * wv + q;
        const float4 v = *(const float4*)&xb[(size_t)d * S_ + s0 + 4 * lk];
        ssql[0] += v.x * v.x;  ssql[1] += v.y * v.y;
        ssql[2] += v.z * v.z;  ssql[3] += v.w * v.w;
        unsigned p0 = pk2(v.x, v.y), p1 = pk2(v.z, v.w);
        // stage 1: exchange halves across lane bit 5
        unsigned mine = (l & 32) ? p0 : p1;
        unsigned oth  = (unsigned)__shfl_xor((int)mine, 32);
        unsigned a0 = (l & 32) ? oth : p0;
        unsigned a1 = (l & 32) ? p1 : oth;
        // stage 2: u16 interleave across lane bit 4
        unsigned r0 = (unsigned)__shfl_xor((int)a0, 16);
        unsigned r1 = (unsigned)__shfl_xor((int)a1, 16);
        unsigned o0, o1;
        if (l & 16) {
            o0 = (r0 >> 16) | (a0 & 0xffff0000u);
            o1 = (r1 >> 16) | (a1 & 0xffff0000u);
        } else {
            o0 = (a0 & 0xffffu) | (r0 << 16);
            o1 = (a1 & 0xffffu) | (r1 << 16);
        }
        // lane holds s = 4lk+q, d-run [16j+4wv, +3] -> one b64 store
        *(u32x2*)&T[sTbase + ((16 * j + 4 * wv) ^ smask)] = (u32x2){o0, o1};
    }
#pragma unroll
    for (int i = 0; i < 4; ++i) atomicAdd(&invSS[4 * lk + i], ssql[i]);
    __syncthreads();   // (A) T + invSS ready

    if (tid < 64) invL[tid] = 1.0f / fmaxf(sqrtf(invSS[tid]), 1e-12f);

    // ---- logits GEMM: wave: [16 k] x [64 s], K-dim d=512 ----
    f32x4 accl[4];
#pragma unroll
    for (int st = 0; st < 4; ++st) accl[st] = (f32x4){0.f, 0.f, 0.f, 0.f};
    const short* wrow = w16 + (size_t)(16 * wv + lk) * D_;
#pragma unroll
    for (int kst = 0; kst < 16; ++kst) {
        short8 af = *(const short8*)&wrow[kst * 32 + q * 8];
        const int off = (kst * 32 + q * 8) ^ rmask;
#pragma unroll
        for (int st = 0; st < 4; ++st) {
            short8 b = *(const short8*)&T[(st * 16 + lk) * 512 + off];
            accl[st] = __builtin_amdgcn_mfma_f32_16x16x32_bf16(af, b, accl[st], 0, 0, 0);
        }
    }
    __syncthreads();   // (B) invL ready

    // ---- softmax over k (no max subtraction; |logit| <= ~1.2) ----
    float e[4][4], invv[4];
#pragma unroll
    for (int st = 0; st < 4; ++st) {
        invv[st] = invL[st * 16 + lk];
        float sm = 0.f;
#pragma unroll
        for (int r = 0; r < 4; ++r) {
            e[st][r] = __expf(accl[st][r] * invv[st]);
            sm += e[st][r];
        }
        sm += __shfl_xor(sm, 16);
        sm += __shfl_xor(sm, 32);
        if (q == 0) wredS[wv][st * 16 + lk] = sm;
    }
    __syncthreads();   // (C) wredS ready

    float asum_loc[4] = {0.f, 0.f, 0.f, 0.f};
#pragma unroll
    for (int st = 0; st < 4; ++st) {
        const int s = st * 16 + lk;
        const float rs = 1.0f / (wredS[0][s] + wredS[1][s]
                               + wredS[2][s] + wredS[3][s]);
#pragma unroll
        for (int r = 0; r < 4; ++r) {
            const float p = e[st][r] * rs;
            aPl[(16 * wv + 4 * q + r) * APL + s] = f2bf(p * invv[st]);
            asum_loc[r] += p;
        }
    }
    __syncthreads();   // (D) aPl ready

    // ---- relay write: aprime[n][k][s0..s0+64) as 128 B coalesced rows ----
    {
        const int kk = tid >> 2;            // 0..63
        const int c0 = (tid & 3) * 16;      // 0,16,32,48
        short8 w0 = *(const short8*)&aPl[kk * APL + c0];
        short8 w1 = *(const short8*)&aPl[kk * APL + c0 + 8];
        short* apb = aprime + (size_t)n * K_ * S_ + (size_t)kk * S_ + s0 + c0;
        *(short8*)apb       = w0;
        *(short8*)(apb + 8) = w1;
    }

    // ---- asum: reduce over lk within 16-lane group, one atomic per k ----
#pragma unroll
    for (int r = 0; r < 4; ++r) {
        float v = asum_loc[r];
        v += __shfl_xor(v, 1);  v += __shfl_xor(v, 2);
        v += __shfl_xor(v, 4);  v += __shfl_xor(v, 8);
        if (lk == 0) atomicAdd(&asum[n * K_ + 16 * wv + 4 * q + r], v);
    }
}

// ---------------------------------------------------------------------------
// kB: LDS-free MFMA GEMM (r0 structure, verified). agg[k][d] over s-split:
//   agg[k][d] = sum_s aprime[k][s] * x[d][s]   (both s-contiguous row-major)
// grid: n(32) x dtile(4 of 128) x split(5 of 320s) = 640 blocks x 256 thr.
// Wave wv: d in [dt*128 + wv*32, +32), all 64 k, 10 K-steps of 32 s.
// Epilogue: atomicAdd into single agg buffer (replaces 5 partials -> saves
// ~33 MB HBM round trip).
// ---------------------------------------------------------------------------
__global__ __launch_bounds__(256) void kB(const float* __restrict__ x,
                                          const short* __restrict__ aprime,
                                          float* __restrict__ agg)
{
    const int bid = blockIdx.x;
    const int n  = bid / 20;
    const int dt = (bid % 20) / 5;
    const int sp = bid % 5;
    const int wv = threadIdx.x >> 6;
    const int l  = threadIdx.x & 63;
    const int lk = l & 15;
    const int q  = l >> 4;
    const int dbase = dt * 128 + wv * 32;

    const short* ap = aprime + (size_t)n * K_ * S_;
    const float* xb = x + (size_t)n * D_ * S_;

    f32x4 acc[4][2];   // [ktile][dsub]
#pragma unroll
    for (int kt = 0; kt < 4; ++kt)
#pragma unroll
        for (int ds = 0; ds < 2; ++ds) acc[kt][ds] = (f32x4){0.f, 0.f, 0.f, 0.f};

    for (int kst = 0; kst < 10; ++kst) {
        const int s = sp * 320 + kst * 32 + q * 8;
        short8 af[4];
#pragma unroll
        for (int kt = 0; kt < 4; ++kt)
            af[kt] = *(const short8*)&ap[(size_t)(kt * 16 + lk) * S_ + s];
        short8 bf[2];
#pragma unroll
        for (int ds = 0; ds < 2; ++ds) {
            const float* xp = &xb[(size_t)(dbase + ds * 16 + lk) * S_ + s];
            float4 v0 = *(const float4*)xp;
            float4 v1 = *(const float4*)(xp + 4);
            short8 b;
            b[0] = f2bf(v0.x); b[1] = f2bf(v0.y); b[2] = f2bf(v0.z); b[3] = f2bf(v0.w);
            b[4] = f2bf(v1.x); b[5] = f2bf(v1.y); b[6] = f2bf(v1.z); b[7] = f2bf(v1.w);
            bf[ds] = b;
        }
#pragma unroll
        for (int kt = 0; kt < 4; ++kt)
#pragma unroll
            for (int ds = 0; ds < 2; ++ds)
                acc[kt][ds] = __builtin_amdgcn_mfma_f32_16x16x32_bf16(af[kt], bf[ds], acc[kt][ds], 0, 0, 0);
    }

    // atomic accumulate: agg[n][k][d]; D row=4q+r (k, 1st op), col=lk (d, 2nd)
    float* ab = agg + (size_t)n * K_ * D_;
#pragma unroll
    for (int kt = 0; kt < 4; ++kt)
#pragma unroll
        for (int ds = 0; ds < 2; ++ds)
#pragma unroll
            for (int r = 0; r < 4; ++r)
                atomicAdd(&ab[(size_t)(kt * 16 + 4 * q + r) * D_ + dbase + ds * 16 + lk],
                          acc[kt][ds][r]);
}

// ---------------------------------------------------------------------------
// kC: vlad = agg - asum*centroid; intra-L2-norm over d; global norm =
// /sqrt(K) = /8 exactly. grid: 2048 blocks x 256 thr (~8.5 MB total traffic).
// ---------------------------------------------------------------------------
__global__ __launch_bounds__(256) void kC(const float* __restrict__ agg,
                                          const float* __restrict__ asum,
                                          const float* __restrict__ cent,
                                          float* __restrict__ out)
{
    __shared__ float red[4];
    const int tid = threadIdx.x;
    const int nk = blockIdx.x;
    const int k = nk & 63;
    const float as = asum[nk];
    const float* cb = cent + (size_t)k * D_;
    const float* ag = agg + (size_t)nk * D_;

    float v0 = ag[tid]       - as * cb[tid];
    float v1 = ag[tid + 256] - as * cb[tid + 256];
    float ssq = v0 * v0 + v1 * v1;

    ssq += __shfl_xor(ssq, 32);
    ssq += __shfl_xor(ssq, 16);
    ssq += __shfl_xor(ssq, 8);
    ssq += __shfl_xor(ssq, 4);
    ssq += __shfl_xor(ssq, 2);
    ssq += __shfl_xor(ssq, 1);
    if ((tid & 63) == 0) red[tid >> 6] = ssq;
    __syncthreads();
    const float total = red[0] + red[1] + red[2] + red[3];
    const float scale = 1.0f / (fmaxf(sqrtf(total), 1e-12f) * 8.0f);

    out[(size_t)nk * D_ + tid]       = v0 * scale;
    out[(size_t)nk * D_ + tid + 256] = v1 * scale;
}

// ---------------------------------------------------------------------------
extern "C" void kernel_launch(void* const* d_in, const int* in_sizes, int n_in,
                              void* d_out, int out_size, void* d_ws, size_t ws_size,
                              hipStream_t stream)
{
    const float* x    = (const float*)d_in[0];   // [32,512,40,40]
    const float* w    = (const float*)d_in[1];   // [64,512]
    const float* cent = (const float*)d_in[2];   // [64,512]
    float* out = (float*)d_out;                  // [32, 32768]

    // ws carve (~10.8 MB), 16B-aligned throughout
    float* agg    = (float*)d_ws;                        // N*K*D fp32 (4.19 MB)
    float* asum   = agg + (size_t)N_ * K_ * D_;          // 2048 fp32
    short* aprime = (short*)(asum + N_ * K_);            // N*K*S bf16 (6.55 MB)
    short* w16    = aprime + (size_t)N_ * K_ * S_;       // 32768 bf16

    // zero agg + asum in one shot (adjacent)
    hipMemsetAsync(agg, 0, ((size_t)N_ * K_ * D_ + N_ * K_) * sizeof(float), stream);

    kW<<<32, 256, 0, stream>>>(w, w16);
    kA<<<N_ * (S_ / 64), 256, 0, stream>>>(x, w16, aprime, asum);
    kB<<<N_ * 4 * 5, 256, 0, stream>>>(x, aprime, agg);
    kC<<<N_ * K_, 256, 0, stream>>>(agg, asum, cent, out);
}

// Round 5
// 222.159 us; speedup vs baseline: 1.5448x; 1.0466x over previous
//
#include <hip/hip_runtime.h>
#include <math.h>

#define N_ 32
#define D_ 512
#define S_ 1600
#define K_ 64

typedef __attribute__((ext_vector_type(8))) short short8;   // 8 bf16 (A/B frag)
typedef __attribute__((ext_vector_type(4))) float f32x4;    // acc frag

// float -> bf16 (round to nearest even), bit pattern in short
static __device__ __forceinline__ short f2bf(float f) {
    unsigned u = __float_as_uint(f);
    u += 0x7fffu + ((u >> 16) & 1u);
    return (short)(u >> 16);
}

// ---------------------------------------------------------------------------
// kW: conv_weight [64][512] fp32 -> bf16
// ---------------------------------------------------------------------------
__global__ __launch_bounds__(256) void kW(const float* __restrict__ w,
                                          short* __restrict__ w16)
{
    int i4 = (blockIdx.x * 256 + threadIdx.x) * 4;   // 32 blocks: 32768 elems
    float4 v = *(const float4*)&w[i4];
    short4 h = {f2bf(v.x), f2bf(v.y), f2bf(v.z), f2bf(v.w)};
    *(short4*)&w16[i4] = h;
}

// ---------------------------------------------------------------------------
// kA: logits -> softmax -> aprime (= p*inv, bf16) + asum.
// LDS-FREE, BARRIER-FREE: one wave (64 thr) per 16 s-columns; grid = 3200.
// B-frags gathered directly from global x (lane (q,lk): s = s0w+lk fixed,
// d = 32*kst + 8*q + j, j=0..7) -> no LDS transpose, no bank conflicts.
// Every x element fetched exactly once (16-lane groups read 64 B segments).
// ssq: lane-local over its 128 d-values + shfl_xor(16,32) over q.
// softmax over 64 k: 16 in-lane values (kt,r) + shfl_xor(16,32) over q.
// No-max softmax (|logits| <= ~||w_k|| ~ 1.2; verified r2-r4).
// MFMA conv: D[row=4q+r][col=lane&15]; row<-1st operand (k), col<-2nd (s).
// ---------------------------------------------------------------------------
__global__ __launch_bounds__(64) void kA(const float* __restrict__ x,
                                         const short* __restrict__ w16,
                                         short* __restrict__ aprime,
                                         float* __restrict__ asum)
{
    const int l   = threadIdx.x;
    const int lk  = l & 15;
    const int q   = l >> 4;
    const int n   = blockIdx.x / 100;
    const int s0w = (blockIdx.x % 100) * 16;

    const float* xcol = x + (size_t)n * D_ * S_ + s0w + lk;  // lane's s-column

    f32x4 accl[4];
#pragma unroll
    for (int kt = 0; kt < 4; ++kt) accl[kt] = (f32x4){0.f, 0.f, 0.f, 0.f};
    float ssq = 0.f;

#pragma unroll 2
    for (int kst = 0; kst < 16; ++kst) {
        // B-frag: 8 strided gathers along d for this lane's s
        float xv[8];
#pragma unroll
        for (int j = 0; j < 8; ++j)
            xv[j] = xcol[(size_t)(kst * 32 + q * 8 + j) * S_];
        short8 bf;
#pragma unroll
        for (int j = 0; j < 8; ++j) {
            ssq += xv[j] * xv[j];
            bf[j] = f2bf(xv[j]);
        }
        // A-frags from w16 (L1/L2-resident, 64 KB) + MFMA
#pragma unroll
        for (int kt = 0; kt < 4; ++kt) {
            short8 af = *(const short8*)&w16[(size_t)(kt * 16 + lk) * D_ + kst * 32 + q * 8];
            accl[kt] = __builtin_amdgcn_mfma_f32_16x16x32_bf16(af, bf, accl[kt], 0, 0, 0);
        }
    }

    // full ssq for this lane's s: sum over the 4 q-groups
    ssq += __shfl_xor(ssq, 16);
    ssq += __shfl_xor(ssq, 32);
    const float inv = 1.0f / fmaxf(sqrtf(ssq), 1e-12f);

    // softmax over all 64 k (16 in-lane + cross-q), no max subtraction
    float e[4][4];
    float sm = 0.f;
#pragma unroll
    for (int kt = 0; kt < 4; ++kt)
#pragma unroll
        for (int r = 0; r < 4; ++r) {
            e[kt][r] = __expf(accl[kt][r] * inv);
            sm += e[kt][r];
        }
    sm += __shfl_xor(sm, 16);
    sm += __shfl_xor(sm, 32);
    const float rs = 1.0f / sm;

    // aprime[n][k][s0w+lk] = bf16(p*inv); asum[n][k] += p (reduce over lk)
    short* apb = aprime + (size_t)n * K_ * S_ + s0w + lk;
#pragma unroll
    for (int kt = 0; kt < 4; ++kt)
#pragma unroll
        for (int r = 0; r < 4; ++r) {
            const float p = e[kt][r] * rs;
            apb[(size_t)(kt * 16 + 4 * q + r) * S_] = f2bf(p * inv);
            float v = p;
            v += __shfl_xor(v, 1);
            v += __shfl_xor(v, 2);
            v += __shfl_xor(v, 4);
            v += __shfl_xor(v, 8);
            if (lk == 0) atomicAdd(&asum[n * K_ + kt * 16 + 4 * q + r], v);
        }
}

// ---------------------------------------------------------------------------
// kB: LDS-free MFMA GEMM (r0/r4 structure, verified). agg[k][d] over s-split:
//   agg[k][d] = sum_s aprime[k][s] * x[d][s]   (both s-contiguous row-major)
// grid: n(32) x dtile(4 of 128) x split(5 of 320s) = 640 blocks x 256 thr.
// Wave wv: d in [dt*128 + wv*32, +32), all 64 k, 10 K-steps of 32 s.
// Epilogue: atomicAdd into single agg buffer.
// ---------------------------------------------------------------------------
__global__ __launch_bounds__(256) void kB(const float* __restrict__ x,
                                          const short* __restrict__ aprime,
                                          float* __restrict__ agg)
{
    const int bid = blockIdx.x;
    const int n  = bid / 20;
    const int dt = (bid % 20) / 5;
    const int sp = bid % 5;
    const int wv = threadIdx.x >> 6;
    const int l  = threadIdx.x & 63;
    const int lk = l & 15;
    const int q  = l >> 4;
    const int dbase = dt * 128 + wv * 32;

    const short* ap = aprime + (size_t)n * K_ * S_;
    const float* xb = x + (size_t)n * D_ * S_;

    f32x4 acc[4][2];   // [ktile][dsub]
#pragma unroll
    for (int kt = 0; kt < 4; ++kt)
#pragma unroll
        for (int ds = 0; ds < 2; ++ds) acc[kt][ds] = (f32x4){0.f, 0.f, 0.f, 0.f};

    for (int kst = 0; kst < 10; ++kst) {
        const int s = sp * 320 + kst * 32 + q * 8;
        short8 af[4];
#pragma unroll
        for (int kt = 0; kt < 4; ++kt)
            af[kt] = *(const short8*)&ap[(size_t)(kt * 16 + lk) * S_ + s];
        short8 bf[2];
#pragma unroll
        for (int ds = 0; ds < 2; ++ds) {
            const float* xp = &xb[(size_t)(dbase + ds * 16 + lk) * S_ + s];
            float4 v0 = *(const float4*)xp;
            float4 v1 = *(const float4*)(xp + 4);
            short8 b;
            b[0] = f2bf(v0.x); b[1] = f2bf(v0.y); b[2] = f2bf(v0.z); b[3] = f2bf(v0.w);
            b[4] = f2bf(v1.x); b[5] = f2bf(v1.y); b[6] = f2bf(v1.z); b[7] = f2bf(v1.w);
            bf[ds] = b;
        }
#pragma unroll
        for (int kt = 0; kt < 4; ++kt)
#pragma unroll
            for (int ds = 0; ds < 2; ++ds)
                acc[kt][ds] = __builtin_amdgcn_mfma_f32_16x16x32_bf16(af[kt], bf[ds], acc[kt][ds], 0, 0, 0);
    }

    // atomic accumulate: agg[n][k][d]; D row=4q+r (k, 1st op), col=lk (d, 2nd)
    float* ab = agg + (size_t)n * K_ * D_;
#pragma unroll
    for (int kt = 0; kt < 4; ++kt)
#pragma unroll
        for (int ds = 0; ds < 2; ++ds)
#pragma unroll
            for (int r = 0; r < 4; ++r)
                atomicAdd(&ab[(size_t)(kt * 16 + 4 * q + r) * D_ + dbase + ds * 16 + lk],
                          acc[kt][ds][r]);
}

// ---------------------------------------------------------------------------
// kC: vlad = agg - asum*centroid; intra-L2-norm over d; global norm =
// /sqrt(K) = /8 exactly. grid: 2048 blocks x 256 thr (~8.5 MB total traffic).
// ---------------------------------------------------------------------------
__global__ __launch_bounds__(256) void kC(const float* __restrict__ agg,
                                          const float* __restrict__ asum,
                                          const float* __restrict__ cent,
                                          float* __restrict__ out)
{
    __shared__ float red[4];
    const int tid = threadIdx.x;
    const int nk = blockIdx.x;
    const int k = nk & 63;
    const float as = asum[nk];
    const float* cb = cent + (size_t)k * D_;
    const float* ag = agg + (size_t)nk * D_;

    float v0 = ag[tid]       - as * cb[tid];
    float v1 = ag[tid + 256] - as * cb[tid + 256];
    float ssq = v0 * v0 + v1 * v1;

    ssq += __shfl_xor(ssq, 32);
    ssq += __shfl_xor(ssq, 16);
    ssq += __shfl_xor(ssq, 8);
    ssq += __shfl_xor(ssq, 4);
    ssq += __shfl_xor(ssq, 2);
    ssq += __shfl_xor(ssq, 1);
    if ((tid & 63) == 0) red[tid >> 6] = ssq;
    __syncthreads();
    const float total = red[0] + red[1] + red[2] + red[3];
    const float scale = 1.0f / (fmaxf(sqrtf(total), 1e-12f) * 8.0f);

    out[(size_t)nk * D_ + tid]       = v0 * scale;
    out[(size_t)nk * D_ + tid + 256] = v1 * scale;
}

// ---------------------------------------------------------------------------
extern "C" void kernel_launch(void* const* d_in, const int* in_sizes, int n_in,
                              void* d_out, int out_size, void* d_ws, size_t ws_size,
                              hipStream_t stream)
{
    const float* x    = (const float*)d_in[0];   // [32,512,40,40]
    const float* w    = (const float*)d_in[1];   // [64,512]
    const float* cent = (const float*)d_in[2];   // [64,512]
    float* out = (float*)d_out;                  // [32, 32768]

    // ws carve (~10.8 MB), 16B-aligned throughout
    float* agg    = (float*)d_ws;                        // N*K*D fp32 (4.19 MB)
    float* asum   = agg + (size_t)N_ * K_ * D_;          // 2048 fp32
    short* aprime = (short*)(asum + N_ * K_);            // N*K*S bf16 (6.55 MB)
    short* w16    = aprime + (size_t)N_ * K_ * S_;       // 32768 bf16

    // zero agg + asum in one shot (adjacent)
    hipMemsetAsync(agg, 0, ((size_t)N_ * K_ * D_ + N_ * K_) * sizeof(float), stream);

    kW<<<32, 256, 0, stream>>>(w, w16);
    kA<<<N_ * (S_ / 16), 64, 0, stream>>>(x, w16, aprime, asum);
    kB<<<N_ * 4 * 5, 256, 0, stream>>>(x, aprime, agg);
    kC<<<N_ * K_, 256, 0, stream>>>(agg, asum, cent, out);
}